// Round 1
// 579.907 us; speedup vs baseline: 1.0325x; 1.0325x over previous
//
#include <hip/hip_runtime.h>
#include <stdint.h>

typedef _Float16 f16x8 __attribute__((ext_vector_type(8)));
typedef _Float16 f16x4 __attribute__((ext_vector_type(4)));
typedef float fx4 __attribute__((ext_vector_type(4)));

static constexpr int S_LEN = 2048;
static constexpr int BATCH = 2;
static constexpr int TOKENS = BATCH * S_LEN;   // 4096
static constexpr int DIM = 2048;
static constexpr int NH = 16;
static constexpr int QR = 1536;
static constexpr int KVR = 512;
static constexpr int DN = 128;
static constexpr int DR = 64;
static constexpr int DV = 128;

// async global->LDS, 16B per lane; LDS dest = wave-uniform base, HW adds lane*16
__device__ __forceinline__ void async16(const _Float16* g, _Float16* lds_base_uniform) {
  __builtin_amdgcn_global_load_lds(
      (const __attribute__((address_space(1))) void*)g,
      (__attribute__((address_space(3))) void*)lds_base_uniform, 16, 0, 0);
}

// ---------------- fused f32 -> f16 conversion (all tensors, one dispatch) ---
struct CvtSegs {
  const float* src[8];
  _Float16* dst[8];
  int n4[8];
  int cum[9];
};
__global__ __launch_bounds__(256) void cvt_all(CvtSegs s) {
  const int b = blockIdx.x;
  int seg = 0;
#pragma unroll
  for (int k = 0; k < 7; ++k) seg += (b >= s.cum[seg + 1]) ? 1 : 0;
  const int i = (b - s.cum[seg]) * 256 + threadIdx.x;
  if (i >= s.n4[seg]) return;
  fx4 v = *(const fx4*)(s.src[seg] + (size_t)i * 4);
  f16x4 o;
  o[0] = (_Float16)v[0]; o[1] = (_Float16)v[1];
  o[2] = (_Float16)v[2]; o[3] = (_Float16)v[3];
  *(f16x4*)(s.dst[seg] + (size_t)i * 4) = o;
}

// ---------------- NT GEMM, double-buffered LDS, ONE barrier per K-iter -----
// C[M,N] = A[M,K] * W[N,K]^T.  128x128 tile, BK=32.
// MODE 0: f16 C0.  MODE 1: f32 C0.  MODE 2: split knope[T,2048] + vT[2048,T].
// MODE 3: split qnope[.,2048] + qpe[.,1024].  MODE 4: split kvc[.,512] + krope[.,64].
template <int MODE>
__global__ __launch_bounds__(256) void gemm_nt(const _Float16* __restrict__ A,
                                               const _Float16* __restrict__ W,
                                               void* __restrict__ C0v,
                                               void* __restrict__ C1v,
                                               int M, int N, int K) {
  __shared__ __attribute__((aligned(16))) _Float16 As[2][128 * 32];
  __shared__ __attribute__((aligned(16))) _Float16 Ws[2][128 * 32];
  const int tid = threadIdx.x;
  const int lane = tid & 63;
  const int wave = tid >> 6;
  const int wr = (wave >> 1) * 64;
  const int wc = (wave & 1) * 64;
  const int m16 = lane & 15;
  const int quad = lane >> 4;
  const int m0 = blockIdx.y * 128;
  const int n0 = blockIdx.x * 128;

  auto stage = [&](int buf, int k0) {
#pragma unroll
    for (int p = 0; p < 2; ++p) {
      const int cb = p * 256 + wave * 64;   // wave-uniform chunk base
      const int ch = cb + lane;
      const int r = ch >> 2;
      const int c8 = (ch & 3) * 8;
      // W rows n0+r may exceed N (N=576 gemm); reads stay inside workspace.
      async16(A + (size_t)(m0 + r) * K + k0 + c8, &As[buf][cb * 8]);
      async16(W + (size_t)(n0 + r) * K + k0 + c8, &Ws[buf][cb * 8]);
    }
  };

  const fx4 fz = {0.f, 0.f, 0.f, 0.f};
  fx4 acc[4][4];
#pragma unroll
  for (int i = 0; i < 4; ++i)
#pragma unroll
    for (int j = 0; j < 4; ++j) acc[i][j] = fz;

  const int nkt = K >> 5;
  stage(0, 0);
  for (int kt = 0; kt < nkt; ++kt) {
    __syncthreads();                       // drains buf[kt&1] loads (in flight all last iter)
    if (kt + 1 < nkt) stage((kt + 1) & 1, (kt + 1) * 32);   // overlaps compute below
    const _Float16* as = As[kt & 1];
    const _Float16* ws = Ws[kt & 1];
    f16x8 af[4], wf[4];
#pragma unroll
    for (int i = 0; i < 4; ++i)
      af[i] = *(const f16x8*)(&as[(wr + i * 16 + m16) * 32 + quad * 8]);
#pragma unroll
    for (int j = 0; j < 4; ++j)
      wf[j] = *(const f16x8*)(&ws[(wc + j * 16 + m16) * 32 + quad * 8]);
#pragma unroll
    for (int i = 0; i < 4; ++i)
#pragma unroll
      for (int j = 0; j < 4; ++j)
        acc[i][j] = __builtin_amdgcn_mfma_f32_16x16x32_f16(af[i], wf[j], acc[i][j], 0, 0, 0);
  }

#pragma unroll
  for (int j = 0; j < 4; ++j) {
    const int col = n0 + wc + j * 16 + m16;
    if (MODE == 2) {
      _Float16* KN = (_Float16*)C0v;
      _Float16* VT = (_Float16*)C1v;
      const int head = col >> 8;
      const int sub = col & 255;
      if (sub < 128) {
#pragma unroll
        for (int i = 0; i < 4; ++i)
#pragma unroll
          for (int r = 0; r < 4; ++r)
            KN[(size_t)(m0 + wr + i * 16 + quad * 4 + r) * 2048 + head * 128 + sub] =
                (_Float16)acc[i][j][r];
      } else {
        const int dv = sub - 128;
#pragma unroll
        for (int i = 0; i < 4; ++i) {
          f16x4 v;
#pragma unroll
          for (int r = 0; r < 4; ++r) v[r] = (_Float16)acc[i][j][r];
          *(f16x4*)(&VT[(size_t)(head * 128 + dv) * TOKENS + m0 + wr + i * 16 + quad * 4]) = v;
        }
      }
    } else if (MODE == 3) {
#pragma unroll
      for (int i = 0; i < 4; ++i)
#pragma unroll
        for (int r = 0; r < 4; ++r) {
          const size_t row = (size_t)(m0 + wr + i * 16 + quad * 4 + r);
          if (col < 2048) ((_Float16*)C0v)[row * 2048 + col] = (_Float16)acc[i][j][r];
          else ((_Float16*)C1v)[row * 1024 + col - 2048] = (_Float16)acc[i][j][r];
        }
    } else if (MODE == 4) {
      if (col < 576) {
#pragma unroll
        for (int i = 0; i < 4; ++i)
#pragma unroll
          for (int r = 0; r < 4; ++r) {
            const size_t row = (size_t)(m0 + wr + i * 16 + quad * 4 + r);
            if (col < 512) ((_Float16*)C0v)[row * 512 + col] = (_Float16)acc[i][j][r];
            else ((_Float16*)C1v)[row * 64 + col - 512] = (_Float16)acc[i][j][r];
          }
      }
    } else {
      if (col < N) {
#pragma unroll
        for (int i = 0; i < 4; ++i)
#pragma unroll
          for (int r = 0; r < 4; ++r) {
            const size_t row = (size_t)(m0 + wr + i * 16 + quad * 4 + r);
            if (MODE == 0) ((_Float16*)C0v)[row * N + col] = (_Float16)acc[i][j][r];
            else ((float*)C0v)[row * N + col] = acc[i][j][r];
          }
      }
    }
  }
}

// ---------------- in-place RMSNorm over f16 rows (fp32 math) ---------------
template <int NC>
__global__ __launch_bounds__(256) void rmsnorm_ip(_Float16* __restrict__ xx,
                                                  const float* __restrict__ w) {
  const int row = blockIdx.x;
  _Float16* p = xx + (size_t)row * NC;
  float ss = 0.f;
  for (int c = threadIdx.x; c < NC; c += 256) {
    const float v = (float)p[c];
    ss += v * v;
  }
#pragma unroll
  for (int d = 1; d < 64; d <<= 1) ss += __shfl_xor(ss, d);
  __shared__ float red[4];
  if ((threadIdx.x & 63) == 0) red[threadIdx.x >> 6] = ss;
  __syncthreads();
  const float rs = rsqrtf((red[0] + red[1] + red[2] + red[3]) * (1.0f / NC) + 1e-6f);
  for (int c = threadIdx.x; c < NC; c += 256)
    p[c] = (_Float16)((float)p[c] * rs * w[c]);
}

// ---------------- in-place RoPE (LLaMA interleaved pairs, d=64) ------------
__global__ void rope_q(_Float16* __restrict__ qpe) {  // [T, NH*64]
  const int idx = blockIdx.x * 256 + threadIdx.x;     // T*NH*32 threads
  const int t = idx >> 9;
  const int rem = idx & 511;
  const int hh = rem >> 5;
  const int i = rem & 31;
  const int s = t & (S_LEN - 1);
  const float fr = exp2f(-(float)i * 0.4152410118609203f);  // log2(1e4)/32
  const float ang = (float)s * fr;
  const float sn = sinf(ang), cs = cosf(ang);
  const size_t base = (size_t)t * (NH * DR) + hh * DR + 2 * i;
  const float x1 = (float)qpe[base];
  const float x2 = (float)qpe[base + 1];
  qpe[base] = (_Float16)(x1 * cs - x2 * sn);
  qpe[base + 1] = (_Float16)(x1 * sn + x2 * cs);
}

__global__ void rope_k(_Float16* __restrict__ kr) {  // [T, 64]
  const int idx = blockIdx.x * 256 + threadIdx.x;    // T*32 threads
  const int t = idx >> 5;
  const int i = idx & 31;
  const int s = t & (S_LEN - 1);
  const float fr = exp2f(-(float)i * 0.4152410118609203f);
  const float ang = (float)s * fr;
  const float sn = sinf(ang), cs = cosf(ang);
  const size_t base = (size_t)t * DR + 2 * i;
  const float x1 = (float)kr[base];
  const float x2 = (float)kr[base + 1];
  kr[base] = (_Float16)(x1 * cs - x2 * sn);
  kr[base + 1] = (_Float16)(x1 * sn + x2 * cs);
}

// ---------------- causal flash attention v4 --------------------------------
// Block = 4 waves x 16 q-rows = 64 q-rows. Each block processes TWO
// complementary q-tiles sequentially (j and 31-j), so every block does
// exactly 66 K-tiles -> uniform work, occupancy stays flat (no causal tail).
// K-tiles (32 keys x 192 dims) staged in LDS chunk-major via global_load_lds,
// double-buffered, ONE __syncthreads per tile. V read direct global->reg
// from vT (L2-served). P transpose via wave-private LDS.
// Softmax in log2 domain (exp2) + defer-max (skip O-rescale when max grows
// <= 10 bits; P bounded by 2^10, safe in f16).
__global__ __launch_bounds__(256, 2) void mla_attn(
    const _Float16* __restrict__ qn,   // [T, NH*128]
    const _Float16* __restrict__ qp,   // [T, NH*64]  roped
    const _Float16* __restrict__ kn,   // [T, NH*128]
    const _Float16* __restrict__ kr,   // [T, 64]     roped
    const _Float16* __restrict__ vT,   // [NH*128, T]
    _Float16* __restrict__ out)        // [T, NH*128]
{
  // chunk-major K: chunk c = ch*32+key (ch 0..23 = 16B chunk of 192-dim, key 0..31)
  __shared__ __attribute__((aligned(16))) _Float16 Ks[2][768 * 8];
  __shared__ __attribute__((aligned(16))) _Float16 Ps[4][16][40];

  const int bid = blockIdx.x;          // 512 = B * NH * 16 pairs
  const int b = bid >> 8;
  const int u = bid & 255;
  const int h = u >> 4;
  const int jp = u & 15;               // pair index
  const int tok0 = b * S_LEN;

  const int tid = threadIdx.x;
  const int lane = tid & 63;
  const int wave = tid >> 6;
  const int m16 = lane & 15;
  const int quad = lane >> 4;

  auto stageK = [&](int buf, int kbase) {
#pragma unroll
    for (int j = 0; j < 3; ++j) {
      const int i = wave * 3 + j;             // instr 0..11
      const int ch = i * 2 + (lane >> 5);     // wave-uniform side of 16
      const int key = lane & 31;
      const _Float16* g = (ch < 16)
          ? kn + (size_t)(tok0 + kbase + key) * 2048 + h * 128 + ch * 8
          : kr + (size_t)(tok0 + kbase + key) * 64 + (ch - 16) * 8;
      async16(g, &Ks[buf][i * 512]);
    }
  };

  const float scale2 = 0.07216878364870323f * 1.4426950408889634f;  // /sqrt(192), log2 dom
  const fx4 fz = {0.f, 0.f, 0.f, 0.f};

  for (int half = 0; half < 2; ++half) {
    const int q32 = half ? (31 - jp) : jp;    // 64-row q-tile index
    const int qb = q32 * 64;
    const int R0 = qb + wave * 16;            // this wave's first q-row

    // ---- Q fragments (A-layout), loaded once per half ----
    f16x8 qf[6];
    {
      const size_t t = (size_t)(tok0 + qb + wave * 16 + m16);
#pragma unroll
      for (int kk = 0; kk < 4; ++kk)
        qf[kk] = *(const f16x8*)(qn + t * 2048 + h * 128 + kk * 32 + quad * 8);
#pragma unroll
      for (int kk = 0; kk < 2; ++kk)
        qf[4 + kk] = *(const f16x8*)(qp + t * 1024 + h * 64 + kk * 32 + quad * 8);
    }

    fx4 oacc[8];
#pragma unroll
    for (int n = 0; n < 8; ++n) oacc[n] = fz;
    float mst[4], lst[4];
#pragma unroll
    for (int r = 0; r < 4; ++r) { mst[r] = -3.0e38f; lst[r] = 0.f; }

    const int nkt = (qb >> 5) + 2;            // key tiles: 0 .. qb+63

    stageK(0, 0);
    for (int kt = 0; kt < nkt; ++kt) {
      const int kbase = kt * 32;
      __syncthreads();                        // buf[kt&1] ready (in flight last iter)
      const bool live = (kbase <= R0 + 15);

      // V loads BEFORE prefetch-issue: consuming them waits vmcnt(12), not the prefetch
      f16x8 vf[8];
      if (live) {
#pragma unroll
        for (int n8 = 0; n8 < 8; ++n8)
          vf[n8] = *(const f16x8*)(vT + (size_t)(h * 128 + n8 * 16 + m16) * TOKENS +
                                   tok0 + kbase + quad * 8);
      }
      if (kt + 1 < nkt) stageK((kt + 1) & 1, kbase + 32);

      if (!live) continue;                    // fully-masked tile for this wave
      const _Float16* ks = Ks[kt & 1];

      // ---- S = Q K^T : 2 key-groups x 6 kk ----
      fx4 sc[2];
      sc[0] = fz; sc[1] = fz;
#pragma unroll
      for (int kk = 0; kk < 6; ++kk) {
#pragma unroll
        for (int n = 0; n < 2; ++n) {
          f16x8 kf = *(const f16x8*)(&ks[(kk * 128 + quad * 32 + n * 16 + m16) * 8]);
          sc[n] = __builtin_amdgcn_mfma_f32_16x16x32_f16(qf[kk], kf, sc[n], 0, 0, 0);
        }
      }

      // ---- online softmax, log2 domain (C/D layout: row=quad*4+r, col=n*16+m16) ----
      const bool needmask = (kbase + 31 > R0);
      float alpha[4];
      bool any_upd = false;
#pragma unroll
      for (int r = 0; r < 4; ++r) {
        float v0 = sc[0][r] * scale2;
        float v1 = sc[1][r] * scale2;
        if (needmask) {
          const int qrow = R0 + quad * 4 + r;
          if (kbase + m16 > qrow)      v0 = -3.0e38f;
          if (kbase + 16 + m16 > qrow) v1 = -3.0e38f;
        }
        float mx = fmaxf(v0, v1);
#pragma unroll
        for (int d = 1; d < 16; d <<= 1) mx = fmaxf(mx, __shfl_xor(mx, d));
        float al = 1.0f;
        if (__any(mx > mst[r] + 10.0f)) {     // defer-max: only rescale on real growth
          const float mn = fmaxf(mst[r], mx);
          al = exp2f(mst[r] - mn);
          mst[r] = mn;
          any_upd = true;
        }
        alpha[r] = al;
        const float p0 = exp2f(v0 - mst[r]);
        const float p1 = exp2f(v1 - mst[r]);
        float ls = p0 + p1;
#pragma unroll
        for (int d = 1; d < 16; d <<= 1) ls += __shfl_xor(ls, d);
        lst[r] = lst[r] * al + ls;
        _Float16* pr = &Ps[wave][quad * 4 + r][0];
        pr[m16] = (_Float16)p0;
        pr[16 + m16] = (_Float16)p1;
      }
      if (any_upd) {
#pragma unroll
        for (int n8 = 0; n8 < 8; ++n8)
#pragma unroll
          for (int r = 0; r < 4; ++r) oacc[n8][r] *= alpha[r];
      }

      // ---- O += P V  (P via wave-private LDS -> A-layout; V from regs) ----
      f16x8 pf = *(const f16x8*)(&Ps[wave][m16][quad * 8]);
#pragma unroll
      for (int n8 = 0; n8 < 8; ++n8)
        oacc[n8] = __builtin_amdgcn_mfma_f32_16x16x32_f16(pf, vf[n8], oacc[n8], 0, 0, 0);
    }

    // ---- epilogue for this half ----
    float inv[4];
#pragma unroll
    for (int r = 0; r < 4; ++r) inv[r] = 1.0f / lst[r];
#pragma unroll
    for (int n8 = 0; n8 < 8; ++n8) {
#pragma unroll
      for (int r = 0; r < 4; ++r) {
        const size_t t = (size_t)(tok0 + qb + wave * 16 + quad * 4 + r);
        out[t * 2048 + h * 128 + n8 * 16 + m16] = (_Float16)(oacc[n8][r] * inv[r]);
      }
    }
  }
}

// ---------------- launch ----------------------------------------------------
extern "C" void kernel_launch(void* const* d_in, const int* in_sizes, int n_in,
                              void* d_out, int out_size, void* d_ws, size_t ws_size,
                              hipStream_t stream) {
  const float* x         = (const float*)d_in[0];
  const float* wq_down   = (const float*)d_in[1];
  const float* q_norm_w  = (const float*)d_in[2];
  const float* wq_up     = (const float*)d_in[3];
  const float* wq_rope   = (const float*)d_in[4];
  const float* wkv_down  = (const float*)d_in[5];
  const float* kv_norm_w = (const float*)d_in[6];
  const float* wkv_up    = (const float*)d_in[7];
  const float* wk_rope   = (const float*)d_in[8];
  const float* wo        = (const float*)d_in[9];
  float* out = (float*)d_out;

  char* ws = (char*)d_ws;
  size_t off = 0;
  auto alloc = [&](size_t bytes) {
    char* p = ws + off;
    off += (bytes + 255) & ~(size_t)255;
    return p;
  };
  _Float16* x_h     = (_Float16*)alloc((size_t)TOKENS * DIM * 2);
  _Float16* wqd_h   = (_Float16*)alloc((size_t)QR * DIM * 2);
  _Float16* wquqr_h = (_Float16*)alloc((size_t)3072 * QR * 2);       // wq_up | wq_rope
  _Float16* wkvdr_h = (_Float16*)alloc((size_t)576 * DIM * 2);       // wkv_down | wk_rope
  _Float16* wkvu_h  = (_Float16*)alloc((size_t)NH * 256 * KVR * 2);
  _Float16* wo_h    = (_Float16*)alloc((size_t)DIM * NH * DV * 2);
  _Float16* qc_h    = (_Float16*)alloc((size_t)TOKENS * QR * 2);
  _Float16* kvc_h   = (_Float16*)alloc((size_t)TOKENS * KVR * 2);
  _Float16* qnope_h = (_Float16*)alloc((size_t)TOKENS * 2048 * 2);
  _Float16* qpe_h   = (_Float16*)alloc((size_t)TOKENS * 1024 * 2);
  _Float16* knope_h = (_Float16*)alloc((size_t)TOKENS * 2048 * 2);
  _Float16* vT_h    = (_Float16*)alloc((size_t)2048 * TOKENS * 2);
  _Float16* krope_h = (_Float16*)alloc((size_t)TOKENS * DR * 2);
  _Float16* attn_h  = (_Float16*)alloc((size_t)TOKENS * 2048 * 2);

  // ---- one fused conversion dispatch ----
  CvtSegs cs;
  const float* srcs[8] = {x, wq_down, wq_up, wq_rope, wkv_down, wk_rope, wkv_up, wo};
  _Float16* dsts[8] = {x_h, wqd_h, wquqr_h, wquqr_h + (size_t)2048 * QR,
                       wkvdr_h, wkvdr_h + (size_t)512 * DIM, wkvu_h, wo_h};
  const size_t ns[8] = {(size_t)TOKENS * DIM, (size_t)QR * DIM, (size_t)2048 * QR,
                        (size_t)1024 * QR, (size_t)KVR * DIM, (size_t)DR * DIM,
                        (size_t)NH * 256 * KVR, (size_t)DIM * NH * DV};
  int cum = 0;
  for (int i = 0; i < 8; ++i) {
    cs.src[i] = srcs[i];
    cs.dst[i] = dsts[i];
    cs.n4[i] = (int)(ns[i] / 4);
    cs.cum[i] = cum;
    cum += (cs.n4[i] + 255) / 256;
  }
  cs.cum[8] = cum;
  cvt_all<<<dim3(cum), 256, 0, stream>>>(cs);

  auto gx = [](int n) { return (unsigned)((n + 127) / 128); };
  const unsigned gm = TOKENS / 128;

  // q path: x -> qc (N=1536)
  gemm_nt<0><<<dim3(gx(QR), gm), 256, 0, stream>>>(x_h, wqd_h, qc_h, nullptr, TOKENS, QR, DIM);
  rmsnorm_ip<QR><<<dim3(TOKENS), 256, 0, stream>>>(qc_h, q_norm_w);
  // kv path fused with rope-key: x -> kvc | krope (N=576)
  gemm_nt<4><<<dim3(gx(576), gm), 256, 0, stream>>>(x_h, wkvdr_h, kvc_h, krope_h, TOKENS, 576, DIM);
  rmsnorm_ip<KVR><<<dim3(TOKENS), 256, 0, stream>>>(kvc_h, kv_norm_w);
  rope_k<<<dim3(TOKENS * 32 / 256), 256, 0, stream>>>(krope_h);
  // q up fused: qc -> qnope | qpe (N=3072)
  gemm_nt<3><<<dim3(gx(3072), gm), 256, 0, stream>>>(qc_h, wquqr_h, qnope_h, qpe_h, TOKENS, 3072, QR);
  rope_q<<<dim3(TOKENS * NH * 32 / 256), 256, 0, stream>>>(qpe_h);
  // kv up-projection, split epilogue: k_nope natural + V transposed
  gemm_nt<2><<<dim3(gx(4096), gm), 256, 0, stream>>>(kvc_h, wkvu_h, knope_h, vT_h, TOKENS, 4096, KVR);
  // attention: 512 blocks, each = one (b,h, complementary q-tile pair), uniform work
  mla_attn<<<dim3(512), 256, 0, stream>>>(qnope_h, qpe_h, knope_h, krope_h, vT_h, attn_h);
  // output projection (fp32 out)
  gemm_nt<1><<<dim3(gx(DIM), gm), 256, 0, stream>>>(attn_h, wo_h, out, nullptr, TOKENS, DIM, NH * DV);
}

// Round 2
// 529.166 us; speedup vs baseline: 1.1315x; 1.0959x over previous
//
#include <hip/hip_runtime.h>
#include <stdint.h>

typedef _Float16 f16x8 __attribute__((ext_vector_type(8)));
typedef _Float16 f16x4 __attribute__((ext_vector_type(4)));
typedef float fx4 __attribute__((ext_vector_type(4)));

static constexpr int S_LEN = 2048;
static constexpr int BATCH = 2;
static constexpr int TOKENS = BATCH * S_LEN;   // 4096
static constexpr int DIM = 2048;
static constexpr int NH = 16;
static constexpr int QR = 1536;
static constexpr int KVR = 512;
static constexpr int DN = 128;
static constexpr int DR = 64;
static constexpr int DV = 128;

// async global->LDS, 16B per lane; LDS dest = wave-uniform base, HW adds lane*16
__device__ __forceinline__ void async16(const _Float16* g, _Float16* lds_base_uniform) {
  __builtin_amdgcn_global_load_lds(
      (const __attribute__((address_space(1))) void*)g,
      (__attribute__((address_space(3))) void*)lds_base_uniform, 16, 0, 0);
}

// intra-16-lane rotate via DPP (VALU, ~4cyc vs ~35cyc ds_swizzle)
#define ROR16(x, ctrl) \
  __uint_as_float(__builtin_amdgcn_update_dpp(__float_as_uint(x), __float_as_uint(x), \
                                              (ctrl), 0xF, 0xF, false))

// ---------------- fused f32 -> f16 conversion (all tensors, one dispatch) ---
struct CvtSegs {
  const float* src[8];
  _Float16* dst[8];
  int n4[8];
  int cum[9];
};
__global__ __launch_bounds__(256) void cvt_all(CvtSegs s) {
  const int b = blockIdx.x;
  int seg = 0;
#pragma unroll
  for (int k = 0; k < 7; ++k) seg += (b >= s.cum[seg + 1]) ? 1 : 0;
  const int i = (b - s.cum[seg]) * 256 + threadIdx.x;
  if (i >= s.n4[seg]) return;
  fx4 v = *(const fx4*)(s.src[seg] + (size_t)i * 4);
  f16x4 o;
  o[0] = (_Float16)v[0]; o[1] = (_Float16)v[1];
  o[2] = (_Float16)v[2]; o[3] = (_Float16)v[3];
  *(f16x4*)(s.dst[seg] + (size_t)i * 4) = o;
}

// ---------------- NT GEMM, double-buffered LDS, ONE barrier per K-iter -----
// C[M,N] = A[M,K] * W[N,K]^T.  128x128 tile, BK=32.
// MODE 0: f16 C0.  MODE 1: f32 C0.  MODE 2: split knope[T,2048] + vT[2048,T].
// MODE 3: split qnope[.,2048] + qpe[.,1024].  MODE 4: split kvc[.,512] + krope[.,64].
template <int MODE>
__global__ __launch_bounds__(256) void gemm_nt(const _Float16* __restrict__ A,
                                               const _Float16* __restrict__ W,
                                               void* __restrict__ C0v,
                                               void* __restrict__ C1v,
                                               int M, int N, int K) {
  __shared__ __attribute__((aligned(16))) _Float16 As[2][128 * 32];
  __shared__ __attribute__((aligned(16))) _Float16 Ws[2][128 * 32];
  const int tid = threadIdx.x;
  const int lane = tid & 63;
  const int wave = tid >> 6;
  const int wr = (wave >> 1) * 64;
  const int wc = (wave & 1) * 64;
  const int m16 = lane & 15;
  const int quad = lane >> 4;
  const int m0 = blockIdx.y * 128;
  const int n0 = blockIdx.x * 128;

  auto stage = [&](int buf, int k0) {
#pragma unroll
    for (int p = 0; p < 2; ++p) {
      const int cb = p * 256 + wave * 64;   // wave-uniform chunk base
      const int ch = cb + lane;
      const int r = ch >> 2;
      const int c8 = (ch & 3) * 8;
      // W rows n0+r may exceed N (N=576 gemm); reads stay inside workspace.
      async16(A + (size_t)(m0 + r) * K + k0 + c8, &As[buf][cb * 8]);
      async16(W + (size_t)(n0 + r) * K + k0 + c8, &Ws[buf][cb * 8]);
    }
  };

  const fx4 fz = {0.f, 0.f, 0.f, 0.f};
  fx4 acc[4][4];
#pragma unroll
  for (int i = 0; i < 4; ++i)
#pragma unroll
    for (int j = 0; j < 4; ++j) acc[i][j] = fz;

  const int nkt = K >> 5;
  stage(0, 0);
  for (int kt = 0; kt < nkt; ++kt) {
    __syncthreads();                       // drains buf[kt&1] loads (in flight all last iter)
    if (kt + 1 < nkt) stage((kt + 1) & 1, (kt + 1) * 32);   // overlaps compute below
    const _Float16* as = As[kt & 1];
    const _Float16* ws = Ws[kt & 1];
    f16x8 af[4], wf[4];
#pragma unroll
    for (int i = 0; i < 4; ++i)
      af[i] = *(const f16x8*)(&as[(wr + i * 16 + m16) * 32 + quad * 8]);
#pragma unroll
    for (int j = 0; j < 4; ++j)
      wf[j] = *(const f16x8*)(&ws[(wc + j * 16 + m16) * 32 + quad * 8]);
#pragma unroll
    for (int i = 0; i < 4; ++i)
#pragma unroll
      for (int j = 0; j < 4; ++j)
        acc[i][j] = __builtin_amdgcn_mfma_f32_16x16x32_f16(af[i], wf[j], acc[i][j], 0, 0, 0);
  }

#pragma unroll
  for (int j = 0; j < 4; ++j) {
    const int col = n0 + wc + j * 16 + m16;
    if (MODE == 2) {
      _Float16* KN = (_Float16*)C0v;
      _Float16* VT = (_Float16*)C1v;
      const int head = col >> 8;
      const int sub = col & 255;
      if (sub < 128) {
#pragma unroll
        for (int i = 0; i < 4; ++i)
#pragma unroll
          for (int r = 0; r < 4; ++r)
            KN[(size_t)(m0 + wr + i * 16 + quad * 4 + r) * 2048 + head * 128 + sub] =
                (_Float16)acc[i][j][r];
      } else {
        const int dv = sub - 128;
#pragma unroll
        for (int i = 0; i < 4; ++i) {
          f16x4 v;
#pragma unroll
          for (int r = 0; r < 4; ++r) v[r] = (_Float16)acc[i][j][r];
          *(f16x4*)(&VT[(size_t)(head * 128 + dv) * TOKENS + m0 + wr + i * 16 + quad * 4]) = v;
        }
      }
    } else if (MODE == 3) {
#pragma unroll
      for (int i = 0; i < 4; ++i)
#pragma unroll
        for (int r = 0; r < 4; ++r) {
          const size_t row = (size_t)(m0 + wr + i * 16 + quad * 4 + r);
          if (col < 2048) ((_Float16*)C0v)[row * 2048 + col] = (_Float16)acc[i][j][r];
          else ((_Float16*)C1v)[row * 1024 + col - 2048] = (_Float16)acc[i][j][r];
        }
    } else if (MODE == 4) {
      if (col < 576) {
#pragma unroll
        for (int i = 0; i < 4; ++i)
#pragma unroll
          for (int r = 0; r < 4; ++r) {
            const size_t row = (size_t)(m0 + wr + i * 16 + quad * 4 + r);
            if (col < 512) ((_Float16*)C0v)[row * 512 + col] = (_Float16)acc[i][j][r];
            else ((_Float16*)C1v)[row * 64 + col - 512] = (_Float16)acc[i][j][r];
          }
      }
    } else {
      if (col < N) {
#pragma unroll
        for (int i = 0; i < 4; ++i)
#pragma unroll
          for (int r = 0; r < 4; ++r) {
            const size_t row = (size_t)(m0 + wr + i * 16 + quad * 4 + r);
            if (MODE == 0) ((_Float16*)C0v)[row * N + col] = (_Float16)acc[i][j][r];
            else ((float*)C0v)[row * N + col] = acc[i][j][r];
          }
      }
    }
  }
}

// ---------------- in-place RMSNorm over f16 rows (fp32 math) ---------------
template <int NC>
__global__ __launch_bounds__(256) void rmsnorm_ip(_Float16* __restrict__ xx,
                                                  const float* __restrict__ w) {
  const int row = blockIdx.x;
  _Float16* p = xx + (size_t)row * NC;
  float ss = 0.f;
  for (int c = threadIdx.x; c < NC; c += 256) {
    const float v = (float)p[c];
    ss += v * v;
  }
#pragma unroll
  for (int d = 1; d < 64; d <<= 1) ss += __shfl_xor(ss, d);
  __shared__ float red[4];
  if ((threadIdx.x & 63) == 0) red[threadIdx.x >> 6] = ss;
  __syncthreads();
  const float rs = rsqrtf((red[0] + red[1] + red[2] + red[3]) * (1.0f / NC) + 1e-6f);
  for (int c = threadIdx.x; c < NC; c += 256)
    p[c] = (_Float16)((float)p[c] * rs * w[c]);
}

// ---------------- in-place RoPE (LLaMA interleaved pairs, d=64) ------------
__global__ void rope_q(_Float16* __restrict__ qpe) {  // [T, NH*64]
  const int idx = blockIdx.x * 256 + threadIdx.x;     // T*NH*32 threads
  const int t = idx >> 9;
  const int rem = idx & 511;
  const int hh = rem >> 5;
  const int i = rem & 31;
  const int s = t & (S_LEN - 1);
  const float fr = exp2f(-(float)i * 0.4152410118609203f);  // log2(1e4)/32
  const float ang = (float)s * fr;
  const float sn = sinf(ang), cs = cosf(ang);
  const size_t base = (size_t)t * (NH * DR) + hh * DR + 2 * i;
  const float x1 = (float)qpe[base];
  const float x2 = (float)qpe[base + 1];
  qpe[base] = (_Float16)(x1 * cs - x2 * sn);
  qpe[base + 1] = (_Float16)(x1 * sn + x2 * cs);
}

__global__ void rope_k(_Float16* __restrict__ kr) {  // [T, 64]
  const int idx = blockIdx.x * 256 + threadIdx.x;    // T*32 threads
  const int t = idx >> 5;
  const int i = idx & 31;
  const int s = t & (S_LEN - 1);
  const float fr = exp2f(-(float)i * 0.4152410118609203f);
  const float ang = (float)s * fr;
  const float sn = sinf(ang), cs = cosf(ang);
  const size_t base = (size_t)t * DR + 2 * i;
  const float x1 = (float)kr[base];
  const float x2 = (float)kr[base + 1];
  kr[base] = (_Float16)(x1 * cs - x2 * sn);
  kr[base + 1] = (_Float16)(x1 * sn + x2 * cs);
}

// ---------------- causal flash attention v5 --------------------------------
// Block = 4 waves x 16 q-rows = 64 q-rows; TWO complementary q-tiles (j,31-j)
// sequentially -> uniform 66 K-tiles/block, flat occupancy.
// K-tile (32x192, 12KB) AND V-tile (32x128, 8KB) staged via global_load_lds,
// double-buffered, prefetched one tile ahead, ONE __syncthreads per tile.
// Softmax reductions via DPP row_ror rotations (VALU) instead of ds_swizzle:
// cuts the per-row serial chain ~4x and frees the LDS pipe for K/V ds_reads.
// log2-domain softmax + defer-max (skip O rescale when max grows <= 10).
__global__ __launch_bounds__(256, 2) void mla_attn(
    const _Float16* __restrict__ qn,   // [T, NH*128]
    const _Float16* __restrict__ qp,   // [T, NH*64]  roped
    const _Float16* __restrict__ kn,   // [T, NH*128]
    const _Float16* __restrict__ kr,   // [T, 64]     roped
    const _Float16* __restrict__ vT,   // [NH*128, T]
    _Float16* __restrict__ out)        // [T, NH*128]
{
  // chunk-major K: chunk c = ch*32+key (ch 0..23 = 16B chunk of 192-dim, key 0..31)
  __shared__ __attribute__((aligned(16))) _Float16 Ks[2][768 * 8];
  // chunk-major V: position p = dv*4 + q' holds vT[dv][kbase + q'*8 .. +7]
  __shared__ __attribute__((aligned(16))) _Float16 Vs[2][512 * 8];
  __shared__ __attribute__((aligned(16))) _Float16 Ps[4][16][40];

  const int bid = blockIdx.x;          // 512 = B * NH * 16 pairs
  const int b = bid >> 8;
  const int u = bid & 255;
  const int h = u >> 4;
  const int jp = u & 15;               // pair index
  const int tok0 = b * S_LEN;

  const int tid = threadIdx.x;
  const int lane = tid & 63;
  const int wave = tid >> 6;
  const int m16 = lane & 15;
  const int quad = lane >> 4;

  auto stageKV = [&](int buf, int kbase) {
#pragma unroll
    for (int j = 0; j < 3; ++j) {
      const int i = wave * 3 + j;             // instr 0..11
      const int ch = i * 2 + (lane >> 5);     // wave-uniform side of 16
      const int key = lane & 31;
      const _Float16* g = (ch < 16)
          ? kn + (size_t)(tok0 + kbase + key) * 2048 + h * 128 + ch * 8
          : kr + (size_t)(tok0 + kbase + key) * 64 + (ch - 16) * 8;
      async16(g, &Ks[buf][i * 512]);
    }
#pragma unroll
    for (int j = 0; j < 2; ++j) {
      const int i = wave * 2 + j;             // instr 0..7
      const int p = i * 64 + lane;            // chunk position 0..511
      const int dv = p >> 2;
      const int qc = p & 3;
      async16(vT + (size_t)(h * 128 + dv) * TOKENS + tok0 + kbase + qc * 8,
              &Vs[buf][i * 512]);
    }
  };

  const float scale2 = 0.07216878364870323f * 1.4426950408889634f;  // /sqrt(192), log2 dom
  const fx4 fz = {0.f, 0.f, 0.f, 0.f};

  for (int half = 0; half < 2; ++half) {
    const int q32 = half ? (31 - jp) : jp;    // 64-row q-tile index
    const int qb = q32 * 64;
    const int R0 = qb + wave * 16;            // this wave's first q-row

    // ---- Q fragments (A-layout), loaded once per half ----
    f16x8 qf[6];
    {
      const size_t t = (size_t)(tok0 + qb + wave * 16 + m16);
#pragma unroll
      for (int kk = 0; kk < 4; ++kk)
        qf[kk] = *(const f16x8*)(qn + t * 2048 + h * 128 + kk * 32 + quad * 8);
#pragma unroll
      for (int kk = 0; kk < 2; ++kk)
        qf[4 + kk] = *(const f16x8*)(qp + t * 1024 + h * 64 + kk * 32 + quad * 8);
    }

    fx4 oacc[8];
#pragma unroll
    for (int n = 0; n < 8; ++n) oacc[n] = fz;
    float mst[4], lst[4];
#pragma unroll
    for (int r = 0; r < 4; ++r) { mst[r] = -3.0e38f; lst[r] = 0.f; }

    const int nkt = (qb >> 5) + 2;            // key tiles: 0 .. qb+63

    stageKV(0, 0);
    for (int kt = 0; kt < nkt; ++kt) {
      const int kbase = kt * 32;
      __syncthreads();                        // buf[kt&1] ready (in flight last iter)
      if (kt + 1 < nkt) stageKV((kt + 1) & 1, kbase + 32);

      const bool live = (kbase <= R0 + 15);
      if (!live) continue;                    // fully-masked tile for this wave
      const _Float16* ks = Ks[kt & 1];
      const _Float16* vs = Vs[kt & 1];

      // ---- S = Q K^T : 2 key-groups x 6 kk ----
      fx4 sc[2];
      sc[0] = fz; sc[1] = fz;
      __builtin_amdgcn_s_setprio(1);
#pragma unroll
      for (int kk = 0; kk < 6; ++kk) {
#pragma unroll
        for (int n = 0; n < 2; ++n) {
          f16x8 kf = *(const f16x8*)(&ks[(kk * 128 + quad * 32 + n * 16 + m16) * 8]);
          sc[n] = __builtin_amdgcn_mfma_f32_16x16x32_f16(qf[kk], kf, sc[n], 0, 0, 0);
        }
      }
      __builtin_amdgcn_s_setprio(0);

      // V fragments from LDS (B-layout): issued now, consumed at PV
      f16x8 vf[8];
#pragma unroll
      for (int n8 = 0; n8 < 8; ++n8)
        vf[n8] = *(const f16x8*)(&vs[((n8 * 16 + m16) * 4 + quad) * 8]);

      // ---- online softmax, log2 dom, DPP reduce (row=quad*4+r, col=n*16+m16) ----
      const bool needmask = (kbase + 31 > R0);
      float alpha[4];
      bool any_upd = false;
#pragma unroll
      for (int r = 0; r < 4; ++r) {
        float v0 = sc[0][r] * scale2;
        float v1 = sc[1][r] * scale2;
        if (needmask) {
          const int qrow = R0 + quad * 4 + r;
          if (kbase + m16 > qrow)      v0 = -3.0e38f;
          if (kbase + 16 + m16 > qrow) v1 = -3.0e38f;
        }
        float mx = fmaxf(v0, v1);
        mx = fmaxf(mx, ROR16(mx, 0x128));
        mx = fmaxf(mx, ROR16(mx, 0x124));
        mx = fmaxf(mx, ROR16(mx, 0x122));
        mx = fmaxf(mx, ROR16(mx, 0x121));
        float al = 1.0f;
        if (__any(mx > mst[r] + 10.0f)) {     // defer-max: only rescale on real growth
          const float mn = fmaxf(mst[r], mx);
          al = exp2f(mst[r] - mn);
          mst[r] = mn;
          any_upd = true;
        }
        alpha[r] = al;
        const float p0 = exp2f(v0 - mst[r]);
        const float p1 = exp2f(v1 - mst[r]);
        float ls = p0 + p1;
        ls += ROR16(ls, 0x128);
        ls += ROR16(ls, 0x124);
        ls += ROR16(ls, 0x122);
        ls += ROR16(ls, 0x121);
        lst[r] = lst[r] * al + ls;
        _Float16* pr = &Ps[wave][quad * 4 + r][0];
        pr[m16] = (_Float16)p0;
        pr[16 + m16] = (_Float16)p1;
      }
      if (any_upd) {
#pragma unroll
        for (int n8 = 0; n8 < 8; ++n8)
#pragma unroll
          for (int r = 0; r < 4; ++r) oacc[n8][r] *= alpha[r];
      }

      // ---- O += P V  (P via wave-private LDS -> A-layout; V from LDS regs) ----
      f16x8 pf = *(const f16x8*)(&Ps[wave][m16][quad * 8]);
      __builtin_amdgcn_s_setprio(1);
#pragma unroll
      for (int n8 = 0; n8 < 8; ++n8)
        oacc[n8] = __builtin_amdgcn_mfma_f32_16x16x32_f16(pf, vf[n8], oacc[n8], 0, 0, 0);
      __builtin_amdgcn_s_setprio(0);
    }

    // ---- epilogue for this half ----
    float inv[4];
#pragma unroll
    for (int r = 0; r < 4; ++r) inv[r] = 1.0f / lst[r];
#pragma unroll
    for (int n8 = 0; n8 < 8; ++n8) {
#pragma unroll
      for (int r = 0; r < 4; ++r) {
        const size_t t = (size_t)(tok0 + qb + wave * 16 + quad * 4 + r);
        out[t * 2048 + h * 128 + n8 * 16 + m16] = (_Float16)(oacc[n8][r] * inv[r]);
      }
    }
  }
}

// ---------------- launch ----------------------------------------------------
extern "C" void kernel_launch(void* const* d_in, const int* in_sizes, int n_in,
                              void* d_out, int out_size, void* d_ws, size_t ws_size,
                              hipStream_t stream) {
  const float* x         = (const float*)d_in[0];
  const float* wq_down   = (const float*)d_in[1];
  const float* q_norm_w  = (const float*)d_in[2];
  const float* wq_up     = (const float*)d_in[3];
  const float* wq_rope   = (const float*)d_in[4];
  const float* wkv_down  = (const float*)d_in[5];
  const float* kv_norm_w = (const float*)d_in[6];
  const float* wkv_up    = (const float*)d_in[7];
  const float* wk_rope   = (const float*)d_in[8];
  const float* wo        = (const float*)d_in[9];
  float* out = (float*)d_out;

  char* ws = (char*)d_ws;
  size_t off = 0;
  auto alloc = [&](size_t bytes) {
    char* p = ws + off;
    off += (bytes + 255) & ~(size_t)255;
    return p;
  };
  _Float16* x_h     = (_Float16*)alloc((size_t)TOKENS * DIM * 2);
  _Float16* wqd_h   = (_Float16*)alloc((size_t)QR * DIM * 2);
  _Float16* wquqr_h = (_Float16*)alloc((size_t)3072 * QR * 2);       // wq_up | wq_rope
  _Float16* wkvdr_h = (_Float16*)alloc((size_t)576 * DIM * 2);       // wkv_down | wk_rope
  _Float16* wkvu_h  = (_Float16*)alloc((size_t)NH * 256 * KVR * 2);
  _Float16* wo_h    = (_Float16*)alloc((size_t)DIM * NH * DV * 2);
  _Float16* qc_h    = (_Float16*)alloc((size_t)TOKENS * QR * 2);
  _Float16* kvc_h   = (_Float16*)alloc((size_t)TOKENS * KVR * 2);
  _Float16* qnope_h = (_Float16*)alloc((size_t)TOKENS * 2048 * 2);
  _Float16* qpe_h   = (_Float16*)alloc((size_t)TOKENS * 1024 * 2);
  _Float16* knope_h = (_Float16*)alloc((size_t)TOKENS * 2048 * 2);
  _Float16* vT_h    = (_Float16*)alloc((size_t)2048 * TOKENS * 2);
  _Float16* krope_h = (_Float16*)alloc((size_t)TOKENS * DR * 2);
  _Float16* attn_h  = (_Float16*)alloc((size_t)TOKENS * 2048 * 2);

  // ---- one fused conversion dispatch ----
  CvtSegs cs;
  const float* srcs[8] = {x, wq_down, wq_up, wq_rope, wkv_down, wk_rope, wkv_up, wo};
  _Float16* dsts[8] = {x_h, wqd_h, wquqr_h, wquqr_h + (size_t)2048 * QR,
                       wkvdr_h, wkvdr_h + (size_t)512 * DIM, wkvu_h, wo_h};
  const size_t ns[8] = {(size_t)TOKENS * DIM, (size_t)QR * DIM, (size_t)2048 * QR,
                        (size_t)1024 * QR, (size_t)KVR * DIM, (size_t)DR * DIM,
                        (size_t)NH * 256 * KVR, (size_t)DIM * NH * DV};
  int cum = 0;
  for (int i = 0; i < 8; ++i) {
    cs.src[i] = srcs[i];
    cs.dst[i] = dsts[i];
    cs.n4[i] = (int)(ns[i] / 4);
    cs.cum[i] = cum;
    cum += (cs.n4[i] + 255) / 256;
  }
  cs.cum[8] = cum;
  cvt_all<<<dim3(cum), 256, 0, stream>>>(cs);

  auto gx = [](int n) { return (unsigned)((n + 127) / 128); };
  const unsigned gm = TOKENS / 128;

  // q path: x -> qc (N=1536)
  gemm_nt<0><<<dim3(gx(QR), gm), 256, 0, stream>>>(x_h, wqd_h, qc_h, nullptr, TOKENS, QR, DIM);
  rmsnorm_ip<QR><<<dim3(TOKENS), 256, 0, stream>>>(qc_h, q_norm_w);
  // kv path fused with rope-key: x -> kvc | krope (N=576)
  gemm_nt<4><<<dim3(gx(576), gm), 256, 0, stream>>>(x_h, wkvdr_h, kvc_h, krope_h, TOKENS, 576, DIM);
  rmsnorm_ip<KVR><<<dim3(TOKENS), 256, 0, stream>>>(kvc_h, kv_norm_w);
  rope_k<<<dim3(TOKENS * 32 / 256), 256, 0, stream>>>(krope_h);
  // q up fused: qc -> qnope | qpe (N=3072)
  gemm_nt<3><<<dim3(gx(3072), gm), 256, 0, stream>>>(qc_h, wquqr_h, qnope_h, qpe_h, TOKENS, 3072, QR);
  rope_q<<<dim3(TOKENS * NH * 32 / 256), 256, 0, stream>>>(qpe_h);
  // kv up-projection, split epilogue: k_nope natural + V transposed
  gemm_nt<2><<<dim3(gx(4096), gm), 256, 0, stream>>>(kvc_h, wkvu_h, knope_h, vT_h, TOKENS, 4096, KVR);
  // attention: 512 blocks, each = one (b,h, complementary q-tile pair), uniform work
  mla_attn<<<dim3(512), 256, 0, stream>>>(qnope_h, qpe_h, knope_h, krope_h, vT_h, attn_h);
  // output projection (fp32 out)
  gemm_nt<1><<<dim3(gx(DIM), gm), 256, 0, stream>>>(attn_h, wo_h, out, nullptr, TOKENS, DIM, NH * DV);
}